// Round 1
// baseline (974.244 us; speedup 1.0000x reference)
//
#include <hip/hip_runtime.h>
#include <hip/hip_bf16.h>
#include <math.h>

// ---------------------------------------------------------------------------
// GCN 2-layer: out = log_softmax( Ahat @ relu(Ahat @ (X W1) + b1) @ W2 + b2 )
// Ahat = D^-1/2 (A + I) D^-1/2, deg counted over dst (incl. self-loop).
//
// Key algebra: Ahat@(H W2) = (Ahat@H)@W2  -> both aggregations act on 32 feats.
// Pre-scale F' = F * dinv  ->  agg[v] = dinv[v] * (F'[v] + sum_{u->v} F'[u]).
// CSR-by-dst built per call (graph-capture safe), aggregations are pure
// gathers (no float atomics).
// ---------------------------------------------------------------------------

#define DIM 32
#define NCLS 40
#define F_IN 512

// ---------------- degree count ----------------
__global__ __launch_bounds__(256) void count_k(const int* __restrict__ dst,
                                               int* __restrict__ counts, int E) {
    int e = blockIdx.x * 256 + threadIdx.x;
    if (e < E) atomicAdd(&counts[dst[e]], 1);
}

__global__ __launch_bounds__(256) void dinv_k(const int* __restrict__ counts,
                                              float* __restrict__ dinv, int n) {
    int v = blockIdx.x * 256 + threadIdx.x;
    if (v < n) dinv[v] = rsqrtf((float)(counts[v] + 1));  // +1 self loop
}

// ---------------- 3-kernel exclusive scan over counts -> rowptr ----------------
__global__ __launch_bounds__(256) void scan1_k(const int* __restrict__ counts,
                                               int* __restrict__ bsum, int n) {
    __shared__ int red[256];
    int i = blockIdx.x * 256 + threadIdx.x;
    red[threadIdx.x] = (i < n) ? counts[i] : 0;
    __syncthreads();
    for (int s = 128; s; s >>= 1) {
        if (threadIdx.x < s) red[threadIdx.x] += red[threadIdx.x + s];
        __syncthreads();
    }
    if (threadIdx.x == 0) bsum[blockIdx.x] = red[0];
}

// single block, nb <= 512
__global__ __launch_bounds__(512) void scan2_k(const int* __restrict__ bsum,
                                               int* __restrict__ boff, int nb,
                                               int* __restrict__ rowptr, int n) {
    __shared__ int sh[512];
    int t = threadIdx.x;
    sh[t] = (t < nb) ? bsum[t] : 0;
    __syncthreads();
    for (int off = 1; off < 512; off <<= 1) {
        int xv = sh[t];
        if (t >= off) xv += sh[t - off];
        __syncthreads();
        sh[t] = xv;
        __syncthreads();
    }
    if (t < nb) boff[t] = (t == 0) ? 0 : sh[t - 1];
    if (t == 0) rowptr[n] = sh[nb - 1];  // total edge count
}

__global__ __launch_bounds__(256) void scan3_k(const int* __restrict__ counts,
                                               const int* __restrict__ boff,
                                               int* __restrict__ rowptr,
                                               int* __restrict__ cursor, int n) {
    __shared__ int sh[256];
    int t = threadIdx.x;
    int i = blockIdx.x * 256 + t;
    sh[t] = (i < n) ? counts[i] : 0;
    __syncthreads();
    for (int off = 1; off < 256; off <<= 1) {
        int xv = sh[t];
        if (t >= off) xv += sh[t - off];
        __syncthreads();
        sh[t] = xv;
        __syncthreads();
    }
    int excl = ((t ? sh[t - 1] : 0)) + boff[blockIdx.x];
    if (i < n) { rowptr[i] = excl; cursor[i] = excl; }
}

// ---------------- CSR fill ----------------
__global__ __launch_bounds__(256) void fill_k(const int* __restrict__ src,
                                              const int* __restrict__ dst,
                                              int* __restrict__ cursor,
                                              int* __restrict__ csr, int E) {
    int e = blockIdx.x * 256 + threadIdx.x;
    if (e >= E) return;
    int d = dst[e];
    int pos = atomicAdd(&cursor[d], 1);
    csr[pos] = src[e];
}

// ---------------- GEMM1: xwp[row][c] = (x[row] . W1[:,c]) * dinv[row] ----------------
// 64-row tiles, K-tiles of 32. x staged transposed [kk][row] (stride 68 keeps
// 16B alignment for ds_read_b128 and staging writes at 2-way conflict = free).
#define GBM 64
__global__ __launch_bounds__(256) void gemm1_k(const float* __restrict__ x,
                                               const float* __restrict__ W1,
                                               const float* __restrict__ dinv,
                                               float* __restrict__ xwp, int n) {
    __shared__ float xs[32 * 68];       // [kk][row], stride 68
    __shared__ float ws[32 * 33];       // [kk][col], stride 33
    int tid = threadIdx.x;
    int base = blockIdx.x * GBM;
    int c = tid & 31;      // output col
    int rg = tid >> 5;     // row group (8 rows each)
    float acc[8] = {0.f, 0.f, 0.f, 0.f, 0.f, 0.f, 0.f, 0.f};

    int lr = tid >> 2;     // load row 0..63
    int lq = tid & 3;      // k-quad 0..3
    int grow = base + lr;
    if (grow >= n) grow = n - 1;  // clamp (stores guarded)
    const float* xrow = x + (size_t)grow * F_IN;
    int wk = tid >> 3;     // 0..31
    int wc = tid & 7;      // 0..7

    for (int k0 = 0; k0 < F_IN; k0 += 32) {
        float4 a0 = *(const float4*)(xrow + k0 + lq * 4);
        float4 a1 = *(const float4*)(xrow + k0 + 16 + lq * 4);
        float4 wv = *(const float4*)(W1 + (size_t)(k0 + wk) * DIM + wc * 4);
        __syncthreads();
        xs[(lq * 4 + 0) * 68 + lr] = a0.x;
        xs[(lq * 4 + 1) * 68 + lr] = a0.y;
        xs[(lq * 4 + 2) * 68 + lr] = a0.z;
        xs[(lq * 4 + 3) * 68 + lr] = a0.w;
        xs[(lq * 4 + 16) * 68 + lr] = a1.x;
        xs[(lq * 4 + 17) * 68 + lr] = a1.y;
        xs[(lq * 4 + 18) * 68 + lr] = a1.z;
        xs[(lq * 4 + 19) * 68 + lr] = a1.w;
        ws[wk * 33 + wc * 4 + 0] = wv.x;
        ws[wk * 33 + wc * 4 + 1] = wv.y;
        ws[wk * 33 + wc * 4 + 2] = wv.z;
        ws[wk * 33 + wc * 4 + 3] = wv.w;
        __syncthreads();
#pragma unroll
        for (int kk = 0; kk < 32; ++kk) {
            float w = ws[kk * 33 + c];
            const float4 b0 = *(const float4*)&xs[kk * 68 + rg * 8];
            const float4 b1 = *(const float4*)&xs[kk * 68 + rg * 8 + 4];
            acc[0] += b0.x * w; acc[1] += b0.y * w;
            acc[2] += b0.z * w; acc[3] += b0.w * w;
            acc[4] += b1.x * w; acc[5] += b1.y * w;
            acc[6] += b1.z * w; acc[7] += b1.w * w;
        }
    }
#pragma unroll
    for (int i = 0; i < 8; ++i) {
        int row = base + rg * 8 + i;
        if (row < n) xwp[(size_t)row * DIM + c] = acc[i] * dinv[row];
    }
}

// ---------------- gather-aggregate ----------------
// mode 1: out = relu(s*dinv[v] + bias[f]) * dinv[v]   (layer1, pre-scaled for L2)
// mode 2: out = s*dinv[v]                              (layer2 pre-GEMM)
__global__ __launch_bounds__(256) void agg_k(const float* __restrict__ F,
                                             const int* __restrict__ rowptr,
                                             const int* __restrict__ csr,
                                             const float* __restrict__ dinv,
                                             const float* __restrict__ bias,
                                             float* __restrict__ out, int n, int mode) {
    int t = blockIdx.x * 256 + threadIdx.x;
    int v = t >> 5;
    int f = t & 31;
    if (v >= n) return;
    float s = F[(size_t)v * DIM + f];  // self loop term (already *dinv[v])
    int e = rowptr[v];
    int end = rowptr[v + 1];
    for (; e + 1 < end; e += 2) {
        int u0 = csr[e];
        int u1 = csr[e + 1];
        s += F[(size_t)u0 * DIM + f];
        s += F[(size_t)u1 * DIM + f];
    }
    if (e < end) s += F[(size_t)csr[e] * DIM + f];
    float dv = dinv[v];
    float r;
    if (mode == 1) {
        r = s * dv + bias[f];
        r = fmaxf(r, 0.f);
        r *= dv;                 // pre-scale for next layer's gather
    } else {
        r = s * dv;
    }
    out[(size_t)v * DIM + f] = r;
}

// ---------------- epilogue: logits = a2 @ W2 + b2, then log_softmax ----------------
// one wave (64 lanes) per node; lanes 0..39 own a class
__global__ __launch_bounds__(256) void final_k(const float* __restrict__ a2,
                                               const float* __restrict__ W2,
                                               const float* __restrict__ b2,
                                               float* __restrict__ out, int n) {
    __shared__ float w2s[DIM * NCLS];
    __shared__ float b2s[NCLS];
    int tid = threadIdx.x;
    for (int i = tid; i < DIM * NCLS; i += 256) w2s[i] = W2[i];
    if (tid < NCLS) b2s[tid] = b2[tid];
    __syncthreads();
    int lane = tid & 63;
    int wv = tid >> 6;
    int v = blockIdx.x * 4 + wv;
    if (v >= n) return;
    float av = (lane < DIM) ? a2[(size_t)v * DIM + lane] : 0.f;
    float logit = -INFINITY;
    if (lane < NCLS) {
        float accv = b2s[lane];
#pragma unroll
        for (int k = 0; k < DIM; ++k) {
            float a = __shfl(av, k);
            accv += a * w2s[k * NCLS + lane];
        }
        logit = accv;
    }
    float m = logit;
    for (int off = 32; off; off >>= 1) m = fmaxf(m, __shfl_xor(m, off));
    float ex = (lane < NCLS) ? __expf(logit - m) : 0.f;
    float ssum = ex;
    for (int off = 32; off; off >>= 1) ssum += __shfl_xor(ssum, off);
    float lse = m + __logf(ssum);
    if (lane < NCLS) out[(size_t)v * NCLS + lane] = logit - lse;
}

// ---------------------------------------------------------------------------
extern "C" void kernel_launch(void* const* d_in, const int* in_sizes, int n_in,
                              void* d_out, int out_size, void* d_ws, size_t ws_size,
                              hipStream_t stream) {
    const float* x  = (const float*)d_in[0];
    const int*   ei = (const int*)d_in[1];
    const float* W1 = (const float*)d_in[2];
    const float* b1 = (const float*)d_in[3];
    const float* W2 = (const float*)d_in[4];
    const float* b2 = (const float*)d_in[5];
    float* out = (float*)d_out;

    int n = in_sizes[0] / F_IN;   // 100000
    int E = in_sizes[1] / 2;      // 3200000
    const int* src = ei;
    const int* dst = ei + E;

    // workspace layout (256B aligned)
    char* w = (char*)d_ws;
    size_t off = 0;
    auto alloc = [&](size_t bytes) -> void* {
        void* p = w + off;
        off += (bytes + 255) & ~(size_t)255;
        return p;
    };
    int NB = (n + 255) / 256;     // 391 (must be <= 512 for scan2)
    int*   counts = (int*)alloc((size_t)n * 4);
    int*   bsum   = (int*)alloc((size_t)NB * 4);
    int*   boff   = (int*)alloc((size_t)NB * 4);
    int*   rowptr = (int*)alloc((size_t)(n + 1) * 4);
    int*   cursor = (int*)alloc((size_t)n * 4);
    int*   csr    = (int*)alloc((size_t)E * 4);
    float* dinv   = (float*)alloc((size_t)n * 4);
    float* xwp    = (float*)alloc((size_t)n * DIM * 4);
    float* hts    = (float*)alloc((size_t)n * DIM * 4);
    float* a2     = (float*)alloc((size_t)n * DIM * 4);
    (void)ws_size;

    hipMemsetAsync(counts, 0, (size_t)n * 4, stream);

    count_k<<<(E + 255) / 256, 256, 0, stream>>>(dst, counts, E);
    dinv_k<<<(n + 255) / 256, 256, 0, stream>>>(counts, dinv, n);
    scan1_k<<<NB, 256, 0, stream>>>(counts, bsum, n);
    scan2_k<<<1, 512, 0, stream>>>(bsum, boff, NB, rowptr, n);
    scan3_k<<<NB, 256, 0, stream>>>(counts, boff, rowptr, cursor, n);
    fill_k<<<(E + 255) / 256, 256, 0, stream>>>(src, dst, cursor, csr, E);

    gemm1_k<<<(n + GBM - 1) / GBM, 256, 0, stream>>>(x, W1, dinv, xwp, n);
    agg_k<<<((size_t)n * DIM + 255) / 256, 256, 0, stream>>>(xwp, rowptr, csr, dinv, b1, hts, n, 1);
    agg_k<<<((size_t)n * DIM + 255) / 256, 256, 0, stream>>>(hts, rowptr, csr, dinv, nullptr, a2, n, 2);
    final_k<<<(n + 3) / 4, 256, 0, stream>>>(a2, W2, b2, out, n);
}

// Round 2
// 587.666 us; speedup vs baseline: 1.6578x; 1.6578x over previous
//
#include <hip/hip_runtime.h>
#include <hip/hip_bf16.h>
#include <math.h>

// ---------------------------------------------------------------------------
// GCN 2-layer: out = log_softmax( Ahat @ relu(Ahat @ (X W1) + b1) @ W2 + b2 )
// Round 2: bucketed counting-sort CSR build (fill_k's 195MB scattered-write
// traffic -> ~26MB coalesced; count_k's 3.2M global atomics -> LDS atomics).
// ---------------------------------------------------------------------------

#define DIM 32
#define NCLS 40
#define F_IN 512
#define BSH 8            // bucket = dst >> 8 (256 nodes/bucket)
#define EPB 8192         // edges per block in hist/part

// ---------------- K1: bucket histogram (LDS-aggregated) ----------------
__global__ __launch_bounds__(256) void hist_k(const int* __restrict__ dst,
                                              int* __restrict__ gh, int E, int nbk) {
    __shared__ int h[512];
    int tid = threadIdx.x;
    h[tid] = 0; h[tid + 256] = 0;
    __syncthreads();
    int base = blockIdx.x * EPB;
#pragma unroll 4
    for (int k = 0; k < EPB / 256; ++k) {
        int e = base + k * 256 + tid;
        if (e < E) atomicAdd(&h[dst[e] >> BSH], 1);
    }
    __syncthreads();
    if (h[tid]) atomicAdd(&gh[tid], h[tid]);
    if (h[tid + 256]) atomicAdd(&gh[tid + 256], h[tid + 256]);
}

// ---------------- K2: scan buckets -> base + cursor (1 block, nbk<=512) ----
__global__ __launch_bounds__(512) void scanb_k(const int* __restrict__ gh,
                                               int* __restrict__ bbase,
                                               int* __restrict__ gcur, int nbk) {
    __shared__ int sh[512];
    int t = threadIdx.x;
    int c = (t < nbk) ? gh[t] : 0;
    sh[t] = c;
    __syncthreads();
    for (int off = 1; off < 512; off <<= 1) {
        int v = sh[t];
        if (t >= off) v += sh[t - off];
        __syncthreads();
        sh[t] = v;
        __syncthreads();
    }
    int excl = sh[t] - c;
    if (t < nbk) { bbase[t] = excl; gcur[t] = excl; }
    if (t == 0) bbase[nbk] = sh[511];   // = E
}

// ---------------- K3: partition pairs into buckets (coalesced runs) --------
__global__ __launch_bounds__(256) void part_k(const int* __restrict__ src,
                                              const int* __restrict__ dst,
                                              int* __restrict__ gcur,
                                              int2* __restrict__ pairs, int E) {
    __shared__ int2 st[EPB];
    __shared__ int h[512];
    __shared__ int hb[512];
    int tid = threadIdx.x;
    h[tid] = 0; h[tid + 256] = 0;
    __syncthreads();
    int base = blockIdx.x * EPB;
#pragma unroll 4
    for (int k = 0; k < EPB / 256; ++k) {
        int e = base + k * 256 + tid;
        if (e < E) {
            int2 p; p.x = src[e]; p.y = dst[e];
            st[k * 256 + tid] = p;
            atomicAdd(&h[p.y >> BSH], 1);
        }
    }
    __syncthreads();
    // reserve contiguous run per touched bucket with one global atomic
    for (int b = tid; b < 512; b += 256) {
        int cnt = h[b];
        hb[b] = cnt ? atomicAdd(&gcur[b], cnt) : 0;
        h[b] = 0;  // reuse as running offset
    }
    __syncthreads();
#pragma unroll 4
    for (int k = 0; k < EPB / 256; ++k) {
        int e = base + k * 256 + tid;
        if (e < E) {
            int2 p = st[k * 256 + tid];
            int b = p.y >> BSH;
            int r = atomicAdd(&h[b], 1);
            pairs[hb[b] + r] = p;
        }
    }
}

// ---------------- K4: per-bucket CSR build + rowptr + dinv (all LDS) -------
__global__ __launch_bounds__(256) void build_k(const int2* __restrict__ pairs,
                                               const int* __restrict__ bbase,
                                               int* __restrict__ rowptr,
                                               int* __restrict__ csr,
                                               float* __restrict__ dinv,
                                               int n, int nbk, int E) {
    __shared__ int cnt[256];
    __shared__ int sc[256];
    __shared__ int cur[256];
    int tid = threadIdx.x;
    int b = blockIdx.x;
    int lo = bbase[b], hi = bbase[b + 1];
    cnt[tid] = 0;
    __syncthreads();
    for (int i = lo + tid; i < hi; i += 256)
        atomicAdd(&cnt[pairs[i].y & 255], 1);
    __syncthreads();
    int c = cnt[tid];
    sc[tid] = c;
    __syncthreads();
    for (int off = 1; off < 256; off <<= 1) {
        int v = sc[tid];
        if (tid >= off) v += sc[tid - off];
        __syncthreads();
        sc[tid] = v;
        __syncthreads();
    }
    int excl = sc[tid] - c;
    int v = (b << BSH) + tid;
    if (v < n) {
        rowptr[v] = lo + excl;
        dinv[v] = rsqrtf((float)(c + 1));   // +1 self loop
    }
    cur[tid] = lo + excl;
    __syncthreads();
    for (int i = lo + tid; i < hi; i += 256) {
        int2 p = pairs[i];
        int pos = atomicAdd(&cur[p.y & 255], 1);
        csr[pos] = p.x;
    }
    if (b == 0 && tid == 0) rowptr[n] = E;
}

// ---------------- GEMM1: xwp[row][c] = (x[row] . W1[:,c]) * dinv[row] ------
#define GBM 64
__global__ __launch_bounds__(256) void gemm1_k(const float* __restrict__ x,
                                               const float* __restrict__ W1,
                                               const float* __restrict__ dinv,
                                               float* __restrict__ xwp, int n) {
    __shared__ float xs[32 * 68];       // [kk][row], stride 68
    __shared__ float ws[32 * 33];       // [kk][col], stride 33
    int tid = threadIdx.x;
    int base = blockIdx.x * GBM;
    int c = tid & 31;      // output col
    int rg = tid >> 5;     // row group (8 rows each)
    float acc[8] = {0.f, 0.f, 0.f, 0.f, 0.f, 0.f, 0.f, 0.f};

    int lr = tid >> 2;     // load row 0..63
    int lq = tid & 3;      // k-quad 0..3
    int grow = base + lr;
    if (grow >= n) grow = n - 1;  // clamp (stores guarded)
    const float* xrow = x + (size_t)grow * F_IN;
    int wk = tid >> 3;     // 0..31
    int wc = tid & 7;      // 0..7

    for (int k0 = 0; k0 < F_IN; k0 += 32) {
        float4 a0 = *(const float4*)(xrow + k0 + lq * 4);
        float4 a1 = *(const float4*)(xrow + k0 + 16 + lq * 4);
        float4 wv = *(const float4*)(W1 + (size_t)(k0 + wk) * DIM + wc * 4);
        __syncthreads();
        xs[(lq * 4 + 0) * 68 + lr] = a0.x;
        xs[(lq * 4 + 1) * 68 + lr] = a0.y;
        xs[(lq * 4 + 2) * 68 + lr] = a0.z;
        xs[(lq * 4 + 3) * 68 + lr] = a0.w;
        xs[(lq * 4 + 16) * 68 + lr] = a1.x;
        xs[(lq * 4 + 17) * 68 + lr] = a1.y;
        xs[(lq * 4 + 18) * 68 + lr] = a1.z;
        xs[(lq * 4 + 19) * 68 + lr] = a1.w;
        ws[wk * 33 + wc * 4 + 0] = wv.x;
        ws[wk * 33 + wc * 4 + 1] = wv.y;
        ws[wk * 33 + wc * 4 + 2] = wv.z;
        ws[wk * 33 + wc * 4 + 3] = wv.w;
        __syncthreads();
#pragma unroll
        for (int kk = 0; kk < 32; ++kk) {
            float w = ws[kk * 33 + c];
            const float4 b0 = *(const float4*)&xs[kk * 68 + rg * 8];
            const float4 b1 = *(const float4*)&xs[kk * 68 + rg * 8 + 4];
            acc[0] += b0.x * w; acc[1] += b0.y * w;
            acc[2] += b0.z * w; acc[3] += b0.w * w;
            acc[4] += b1.x * w; acc[5] += b1.y * w;
            acc[6] += b1.z * w; acc[7] += b1.w * w;
        }
    }
#pragma unroll
    for (int i = 0; i < 8; ++i) {
        int row = base + rg * 8 + i;
        if (row < n) xwp[(size_t)row * DIM + c] = acc[i] * dinv[row];
    }
}

// ---------------- gather-aggregate (8 lanes/node, float4) ----------------
// mode 1: out = relu(s*dinv[v] + bias) * dinv[v]   (layer1, pre-scaled for L2)
// mode 2: out = s*dinv[v]                          (layer2 pre-GEMM)
__global__ __launch_bounds__(256) void agg_k(const float* __restrict__ F,
                                             const int* __restrict__ rowptr,
                                             const int* __restrict__ csr,
                                             const float* __restrict__ dinv,
                                             const float* __restrict__ bias,
                                             float* __restrict__ out, int n, int mode) {
    int t = blockIdx.x * 256 + threadIdx.x;
    int v = t >> 3;
    int f4 = t & 7;          // owns feats [f4*4, f4*4+4)
    if (v >= n) return;
    const float4* Fv = (const float4*)F;
    float4 s = Fv[(size_t)v * 8 + f4];     // self-loop term (already *dinv)
    int e = rowptr[v];
    int end = rowptr[v + 1];
    for (; e + 1 < end; e += 2) {
        int u0 = csr[e];
        int u1 = csr[e + 1];
        float4 a = Fv[(size_t)u0 * 8 + f4];
        float4 bq = Fv[(size_t)u1 * 8 + f4];
        s.x += a.x + bq.x; s.y += a.y + bq.y;
        s.z += a.z + bq.z; s.w += a.w + bq.w;
    }
    if (e < end) {
        float4 a = Fv[(size_t)csr[e] * 8 + f4];
        s.x += a.x; s.y += a.y; s.z += a.z; s.w += a.w;
    }
    float dv = dinv[v];
    float4 r;
    if (mode == 1) {
        float4 bb = *(const float4*)(bias + f4 * 4);
        r.x = fmaxf(s.x * dv + bb.x, 0.f) * dv;
        r.y = fmaxf(s.y * dv + bb.y, 0.f) * dv;
        r.z = fmaxf(s.z * dv + bb.z, 0.f) * dv;
        r.w = fmaxf(s.w * dv + bb.w, 0.f) * dv;
    } else {
        r.x = s.x * dv; r.y = s.y * dv; r.z = s.z * dv; r.w = s.w * dv;
    }
    ((float4*)out)[(size_t)v * 8 + f4] = r;
}

// ---------------- epilogue: logits = a2 @ W2 + b2, then log_softmax --------
__global__ __launch_bounds__(256) void final_k(const float* __restrict__ a2,
                                               const float* __restrict__ W2,
                                               const float* __restrict__ b2,
                                               float* __restrict__ out, int n) {
    __shared__ float w2s[DIM * NCLS];
    __shared__ float b2s[NCLS];
    int tid = threadIdx.x;
    for (int i = tid; i < DIM * NCLS; i += 256) w2s[i] = W2[i];
    if (tid < NCLS) b2s[tid] = b2[tid];
    __syncthreads();
    int lane = tid & 63;
    int wv = tid >> 6;
    int v = blockIdx.x * 4 + wv;
    if (v >= n) return;
    float av = (lane < DIM) ? a2[(size_t)v * DIM + lane] : 0.f;
    float logit = -INFINITY;
    if (lane < NCLS) {
        float accv = b2s[lane];
#pragma unroll
        for (int k = 0; k < DIM; ++k) {
            float a = __shfl(av, k);
            accv += a * w2s[k * NCLS + lane];
        }
        logit = accv;
    }
    float m = logit;
    for (int off = 32; off; off >>= 1) m = fmaxf(m, __shfl_xor(m, off));
    float ex = (lane < NCLS) ? __expf(logit - m) : 0.f;
    float ssum = ex;
    for (int off = 32; off; off >>= 1) ssum += __shfl_xor(ssum, off);
    float lse = m + __logf(ssum);
    if (lane < NCLS) out[(size_t)v * NCLS + lane] = logit - lse;
}

// ---------------------------------------------------------------------------
extern "C" void kernel_launch(void* const* d_in, const int* in_sizes, int n_in,
                              void* d_out, int out_size, void* d_ws, size_t ws_size,
                              hipStream_t stream) {
    const float* x  = (const float*)d_in[0];
    const int*   ei = (const int*)d_in[1];
    const float* W1 = (const float*)d_in[2];
    const float* b1 = (const float*)d_in[3];
    const float* W2 = (const float*)d_in[4];
    const float* b2 = (const float*)d_in[5];
    float* out = (float*)d_out;

    int n = in_sizes[0] / F_IN;   // 100000
    int E = in_sizes[1] / 2;      // 3200000
    const int* src = ei;
    const int* dst = ei + E;
    int nbk = (n + 255) >> BSH;   // 391 (<=512)

    // workspace layout (256B aligned)
    char* w = (char*)d_ws;
    size_t off = 0;
    auto alloc = [&](size_t bytes) -> void* {
        void* p = w + off;
        off += (bytes + 255) & ~(size_t)255;
        return p;
    };
    size_t featB = (size_t)n * DIM * 4;            // 12.8 MB (mult of 256)
    int*   csr    = (int*)alloc((size_t)E * 4);    // 12.8 MB
    char*  pairsR = (char*)alloc((size_t)E * 8);   // 25.6 MB (aliased below)
    float* a2     = (float*)alloc(featB);
    int*   rowptr = (int*)alloc((size_t)(n + 1) * 4);
    float* dinv   = (float*)alloc((size_t)n * 4);
    int*   gh     = (int*)alloc(512 * 4);
    int*   bbase  = (int*)alloc(513 * 4);
    int*   gcur   = (int*)alloc(512 * 4);
    (void)ws_size;

    int2*  pairs = (int2*)pairsR;                  // live: K3..K4
    float* xwp   = (float*)pairsR;                 // live: gemm1..agg1 (after K4)
    float* hts   = (float*)(pairsR + featB);       // live: agg1..agg2

    hipMemsetAsync(gh, 0, 512 * 4, stream);

    int nebk = (E + EPB - 1) / EPB;   // 391
    hist_k <<<nebk, 256, 0, stream>>>(dst, gh, E, nbk);
    scanb_k<<<1, 512, 0, stream>>>(gh, bbase, gcur, nbk);
    part_k <<<nebk, 256, 0, stream>>>(src, dst, gcur, pairs, E);
    build_k<<<nbk, 256, 0, stream>>>(pairs, bbase, rowptr, csr, dinv, n, nbk, E);

    gemm1_k<<<(n + GBM - 1) / GBM, 256, 0, stream>>>(x, W1, dinv, xwp, n);
    agg_k<<<((size_t)n * 8 + 255) / 256, 256, 0, stream>>>(xwp, rowptr, csr, dinv, b1, hts, n, 1);
    agg_k<<<((size_t)n * 8 + 255) / 256, 256, 0, stream>>>(hts, rowptr, csr, dinv, nullptr, a2, n, 2);
    final_k<<<(n + 3) / 4, 256, 0, stream>>>(a2, W2, b2, out, n);
}

// Round 3
// 532.273 us; speedup vs baseline: 1.8303x; 1.1041x over previous
//
#include <hip/hip_runtime.h>
#include <hip/hip_bf16.h>
#include <math.h>

// ---------------------------------------------------------------------------
// GCN 2-layer: out = log_softmax( Ahat @ relu(Ahat @ (X W1) + b1) @ W2 + b2 )
// Round 3: bf16 intermediate feature storage (halves gather traffic, fp32
// accumulation), 4-lane/node uint4 gathers, agg2+W2+log_softmax fused.
// ---------------------------------------------------------------------------

#define DIM 32
#define NCLS 40
#define F_IN 512
#define BSH 8            // bucket = dst >> 8 (256 nodes/bucket)
#define EPB 8192         // edges per block in hist/part

// ---- bf16 helpers (RNE pack, exact unpack) ----
__device__ __forceinline__ unsigned int bf16rne(float x) {
    unsigned int u = __float_as_uint(x);
    return (u + 0x7fffu + ((u >> 16) & 1u)) >> 16;
}
__device__ __forceinline__ unsigned int packpair(float lo, float hi) {
    return bf16rne(lo) | (bf16rne(hi) << 16);
}
__device__ __forceinline__ void unpack8(uint4 u, float* f) {
    f[0] = __uint_as_float(u.x << 16);
    f[1] = __uint_as_float(u.x & 0xffff0000u);
    f[2] = __uint_as_float(u.y << 16);
    f[3] = __uint_as_float(u.y & 0xffff0000u);
    f[4] = __uint_as_float(u.z << 16);
    f[5] = __uint_as_float(u.z & 0xffff0000u);
    f[6] = __uint_as_float(u.w << 16);
    f[7] = __uint_as_float(u.w & 0xffff0000u);
}

// ---------------- K1: bucket histogram (LDS-aggregated) ----------------
__global__ __launch_bounds__(256) void hist_k(const int* __restrict__ dst,
                                              int* __restrict__ gh, int E, int nbk) {
    __shared__ int h[512];
    int tid = threadIdx.x;
    h[tid] = 0; h[tid + 256] = 0;
    __syncthreads();
    int base = blockIdx.x * EPB;
#pragma unroll 4
    for (int k = 0; k < EPB / 256; ++k) {
        int e = base + k * 256 + tid;
        if (e < E) atomicAdd(&h[dst[e] >> BSH], 1);
    }
    __syncthreads();
    if (h[tid]) atomicAdd(&gh[tid], h[tid]);
    if (h[tid + 256]) atomicAdd(&gh[tid + 256], h[tid + 256]);
}

// ---------------- K2: scan buckets -> base + cursor (1 block, nbk<=512) ----
__global__ __launch_bounds__(512) void scanb_k(const int* __restrict__ gh,
                                               int* __restrict__ bbase,
                                               int* __restrict__ gcur, int nbk) {
    __shared__ int sh[512];
    int t = threadIdx.x;
    int c = (t < nbk) ? gh[t] : 0;
    sh[t] = c;
    __syncthreads();
    for (int off = 1; off < 512; off <<= 1) {
        int v = sh[t];
        if (t >= off) v += sh[t - off];
        __syncthreads();
        sh[t] = v;
        __syncthreads();
    }
    int excl = sh[t] - c;
    if (t < nbk) { bbase[t] = excl; gcur[t] = excl; }
    if (t == 0) bbase[nbk] = sh[511];   // = E
}

// ---------------- K3: partition pairs into buckets (coalesced runs) --------
__global__ __launch_bounds__(256) void part_k(const int* __restrict__ src,
                                              const int* __restrict__ dst,
                                              int* __restrict__ gcur,
                                              int2* __restrict__ pairs, int E) {
    __shared__ int2 st[EPB];
    __shared__ int h[512];
    __shared__ int hb[512];
    int tid = threadIdx.x;
    h[tid] = 0; h[tid + 256] = 0;
    __syncthreads();
    int base = blockIdx.x * EPB;
#pragma unroll 4
    for (int k = 0; k < EPB / 256; ++k) {
        int e = base + k * 256 + tid;
        if (e < E) {
            int2 p; p.x = src[e]; p.y = dst[e];
            st[k * 256 + tid] = p;
            atomicAdd(&h[p.y >> BSH], 1);
        }
    }
    __syncthreads();
    for (int b = tid; b < 512; b += 256) {
        int cnt = h[b];
        hb[b] = cnt ? atomicAdd(&gcur[b], cnt) : 0;
        h[b] = 0;  // reuse as running offset
    }
    __syncthreads();
#pragma unroll 4
    for (int k = 0; k < EPB / 256; ++k) {
        int e = base + k * 256 + tid;
        if (e < E) {
            int2 p = st[k * 256 + tid];
            int b = p.y >> BSH;
            int r = atomicAdd(&h[b], 1);
            pairs[hb[b] + r] = p;
        }
    }
}

// ---------------- K4: per-bucket CSR build + rowptr + dinv (all LDS) -------
__global__ __launch_bounds__(256) void build_k(const int2* __restrict__ pairs,
                                               const int* __restrict__ bbase,
                                               int* __restrict__ rowptr,
                                               int* __restrict__ csr,
                                               float* __restrict__ dinv,
                                               int n, int nbk, int E) {
    __shared__ int cnt[256];
    __shared__ int sc[256];
    __shared__ int cur[256];
    int tid = threadIdx.x;
    int b = blockIdx.x;
    int lo = bbase[b], hi = bbase[b + 1];
    cnt[tid] = 0;
    __syncthreads();
    for (int i = lo + tid; i < hi; i += 256)
        atomicAdd(&cnt[pairs[i].y & 255], 1);
    __syncthreads();
    int c = cnt[tid];
    sc[tid] = c;
    __syncthreads();
    for (int off = 1; off < 256; off <<= 1) {
        int v = sc[tid];
        if (tid >= off) v += sc[tid - off];
        __syncthreads();
        sc[tid] = v;
        __syncthreads();
    }
    int excl = sc[tid] - c;
    int v = (b << BSH) + tid;
    if (v < n) {
        rowptr[v] = lo + excl;
        dinv[v] = rsqrtf((float)(c + 1));   // +1 self loop
    }
    cur[tid] = lo + excl;
    __syncthreads();
    for (int i = lo + tid; i < hi; i += 256) {
        int2 p = pairs[i];
        int pos = atomicAdd(&cur[p.y & 255], 1);
        csr[pos] = p.x;
    }
    if (b == 0 && tid == 0) rowptr[n] = E;
}

// ---------------- GEMM1: xwp[row][c] = bf16((x[row].W1[:,c]) * dinv[row]) --
#define GBM 64
__global__ __launch_bounds__(256) void gemm1_k(const float* __restrict__ x,
                                               const float* __restrict__ W1,
                                               const float* __restrict__ dinv,
                                               unsigned short* __restrict__ xwp, int n) {
    __shared__ float xs[32 * 68];       // [kk][row], stride 68
    __shared__ float ws[32 * 33];       // [kk][col], stride 33
    int tid = threadIdx.x;
    int base = blockIdx.x * GBM;
    int c = tid & 31;      // output col
    int rg = tid >> 5;     // row group (8 rows each)
    float acc[8] = {0.f, 0.f, 0.f, 0.f, 0.f, 0.f, 0.f, 0.f};

    int lr = tid >> 2;     // load row 0..63
    int lq = tid & 3;      // k-quad 0..3
    int grow = base + lr;
    if (grow >= n) grow = n - 1;  // clamp (stores guarded)
    const float* xrow = x + (size_t)grow * F_IN;
    int wk = tid >> 3;     // 0..31
    int wc = tid & 7;      // 0..7

    for (int k0 = 0; k0 < F_IN; k0 += 32) {
        float4 a0 = *(const float4*)(xrow + k0 + lq * 4);
        float4 a1 = *(const float4*)(xrow + k0 + 16 + lq * 4);
        float4 wv = *(const float4*)(W1 + (size_t)(k0 + wk) * DIM + wc * 4);
        __syncthreads();
        xs[(lq * 4 + 0) * 68 + lr] = a0.x;
        xs[(lq * 4 + 1) * 68 + lr] = a0.y;
        xs[(lq * 4 + 2) * 68 + lr] = a0.z;
        xs[(lq * 4 + 3) * 68 + lr] = a0.w;
        xs[(lq * 4 + 16) * 68 + lr] = a1.x;
        xs[(lq * 4 + 17) * 68 + lr] = a1.y;
        xs[(lq * 4 + 18) * 68 + lr] = a1.z;
        xs[(lq * 4 + 19) * 68 + lr] = a1.w;
        ws[wk * 33 + wc * 4 + 0] = wv.x;
        ws[wk * 33 + wc * 4 + 1] = wv.y;
        ws[wk * 33 + wc * 4 + 2] = wv.z;
        ws[wk * 33 + wc * 4 + 3] = wv.w;
        __syncthreads();
#pragma unroll
        for (int kk = 0; kk < 32; ++kk) {
            float w = ws[kk * 33 + c];
            const float4 b0 = *(const float4*)&xs[kk * 68 + rg * 8];
            const float4 b1 = *(const float4*)&xs[kk * 68 + rg * 8 + 4];
            acc[0] += b0.x * w; acc[1] += b0.y * w;
            acc[2] += b0.z * w; acc[3] += b0.w * w;
            acc[4] += b1.x * w; acc[5] += b1.y * w;
            acc[6] += b1.z * w; acc[7] += b1.w * w;
        }
    }
#pragma unroll
    for (int i = 0; i < 8; ++i) {
        int row = base + rg * 8 + i;
        if (row < n)
            xwp[(size_t)row * DIM + c] = (unsigned short)bf16rne(acc[i] * dinv[row]);
    }
}

// ---------------- agg1: hts = bf16( relu(agg*dinv + b1) * dinv ) ----------
// 4 lanes/node, lane owns 8 feats (one uint4 = 8 bf16 = 16B)
__global__ __launch_bounds__(256) void agg1_k(const uint4* __restrict__ F,
                                              const int* __restrict__ rowptr,
                                              const int* __restrict__ csr,
                                              const float* __restrict__ dinv,
                                              const float* __restrict__ bias,
                                              uint4* __restrict__ out, int n) {
    int t = blockIdx.x * 256 + threadIdx.x;
    int v = t >> 2;
    int f8 = t & 3;          // owns feats [f8*8, f8*8+8)
    if (v >= n) return;
    float s[8], tmp[8];
    unpack8(F[(size_t)v * 4 + f8], s);   // self-loop (already *dinv)
    int e = rowptr[v];
    int end = rowptr[v + 1];
    for (; e + 1 < end; e += 2) {
        int u0 = csr[e];
        int u1 = csr[e + 1];
        uint4 ua = F[(size_t)u0 * 4 + f8];
        uint4 ub = F[(size_t)u1 * 4 + f8];
        unpack8(ua, tmp);
#pragma unroll
        for (int j = 0; j < 8; ++j) s[j] += tmp[j];
        unpack8(ub, tmp);
#pragma unroll
        for (int j = 0; j < 8; ++j) s[j] += tmp[j];
    }
    if (e < end) {
        unpack8(F[(size_t)csr[e] * 4 + f8], tmp);
#pragma unroll
        for (int j = 0; j < 8; ++j) s[j] += tmp[j];
    }
    float dv = dinv[v];
    float4 b0 = *(const float4*)(bias + f8 * 8);
    float4 b1 = *(const float4*)(bias + f8 * 8 + 4);
    float bb[8] = {b0.x, b0.y, b0.z, b0.w, b1.x, b1.y, b1.z, b1.w};
    float r[8];
#pragma unroll
    for (int j = 0; j < 8; ++j) r[j] = fmaxf(s[j] * dv + bb[j], 0.f) * dv;
    uint4 o;
    o.x = packpair(r[0], r[1]);
    o.y = packpair(r[2], r[3]);
    o.z = packpair(r[4], r[5]);
    o.w = packpair(r[6], r[7]);
    out[(size_t)v * 4 + f8] = o;
}

// ---------------- fused agg2 + (a2 @ W2 + b2) + log_softmax ----------------
// block = 256 threads = 64 nodes x 4 lanes; a2 tile through LDS
__global__ __launch_bounds__(256) void agg2final_k(const uint4* __restrict__ F,
                                                   const int* __restrict__ rowptr,
                                                   const int* __restrict__ csr,
                                                   const float* __restrict__ dinv,
                                                   const float* __restrict__ W2,
                                                   const float* __restrict__ b2,
                                                   float* __restrict__ out, int n) {
    __shared__ float w2s[DIM * NCLS];   // 1280 floats
    __shared__ float b2s[NCLS];
    __shared__ float a2s[64 * 33];      // 64 nodes x 32 feats, pad 33
    int tid = threadIdx.x;
    for (int i = tid; i < DIM * NCLS; i += 256) w2s[i] = W2[i];
    if (tid < NCLS) b2s[tid] = b2[tid];

    int nl = tid >> 2;       // node-local 0..63
    int f8 = tid & 3;
    int v = blockIdx.x * 64 + nl;
    if (v < n) {
        float s[8], tmp[8];
        unpack8(F[(size_t)v * 4 + f8], s);
        int e = rowptr[v];
        int end = rowptr[v + 1];
        for (; e + 1 < end; e += 2) {
            int u0 = csr[e];
            int u1 = csr[e + 1];
            uint4 ua = F[(size_t)u0 * 4 + f8];
            uint4 ub = F[(size_t)u1 * 4 + f8];
            unpack8(ua, tmp);
#pragma unroll
            for (int j = 0; j < 8; ++j) s[j] += tmp[j];
            unpack8(ub, tmp);
#pragma unroll
            for (int j = 0; j < 8; ++j) s[j] += tmp[j];
        }
        if (e < end) {
            unpack8(F[(size_t)csr[e] * 4 + f8], tmp);
#pragma unroll
            for (int j = 0; j < 8; ++j) s[j] += tmp[j];
        }
        float dv = dinv[v];
#pragma unroll
        for (int j = 0; j < 8; ++j) a2s[nl * 33 + f8 * 8 + j] = s[j] * dv;
    }
    __syncthreads();

    // phase B: each thread computes 10 classes for its node
    int q = f8;              // class group: classes q*10 .. q*10+9
    float lg[10];
#pragma unroll
    for (int c = 0; c < 10; ++c) lg[c] = b2s[q * 10 + c];
#pragma unroll
    for (int k = 0; k < DIM; ++k) {
        float a = a2s[nl * 33 + k];
        const float* wr = &w2s[k * NCLS + q * 10];
#pragma unroll
        for (int c = 0; c < 10; ++c) lg[c] += a * wr[c];
    }
    float m = lg[0];
#pragma unroll
    for (int c = 1; c < 10; ++c) m = fmaxf(m, lg[c]);
    m = fmaxf(m, __shfl_xor(m, 1));
    m = fmaxf(m, __shfl_xor(m, 2));
    float ssum = 0.f;
#pragma unroll
    for (int c = 0; c < 10; ++c) ssum += __expf(lg[c] - m);
    ssum += __shfl_xor(ssum, 1);
    ssum += __shfl_xor(ssum, 2);
    float lse = m + __logf(ssum);
    if (v < n) {
        float* o = out + (size_t)v * NCLS + q * 10;
#pragma unroll
        for (int c = 0; c < 10; ++c) o[c] = lg[c] - lse;
    }
}

// ---------------------------------------------------------------------------
extern "C" void kernel_launch(void* const* d_in, const int* in_sizes, int n_in,
                              void* d_out, int out_size, void* d_ws, size_t ws_size,
                              hipStream_t stream) {
    const float* x  = (const float*)d_in[0];
    const int*   ei = (const int*)d_in[1];
    const float* W1 = (const float*)d_in[2];
    const float* b1 = (const float*)d_in[3];
    const float* W2 = (const float*)d_in[4];
    const float* b2 = (const float*)d_in[5];
    float* out = (float*)d_out;

    int n = in_sizes[0] / F_IN;   // 100000
    int E = in_sizes[1] / 2;      // 3200000
    const int* src = ei;
    const int* dst = ei + E;
    int nbk = (n + 255) >> BSH;   // 391 (<=512)

    // workspace layout (256B aligned)
    char* w = (char*)d_ws;
    size_t off = 0;
    auto alloc = [&](size_t bytes) -> void* {
        void* p = w + off;
        off += (bytes + 255) & ~(size_t)255;
        return p;
    };
    size_t featB2 = ((size_t)n * DIM * 2 + 255) & ~(size_t)255;  // 6.4 MB bf16
    int*   csr    = (int*)alloc((size_t)E * 4);    // 12.8 MB
    char*  pairsR = (char*)alloc((size_t)E * 8);   // 25.6 MB (aliased below)
    int*   rowptr = (int*)alloc((size_t)(n + 1) * 4);
    float* dinv   = (float*)alloc((size_t)n * 4);
    int*   gh     = (int*)alloc(512 * 4);
    int*   bbase  = (int*)alloc(513 * 4);
    int*   gcur   = (int*)alloc(512 * 4);
    (void)ws_size;

    int2*           pairs = (int2*)pairsR;               // live: K3..K4
    unsigned short* xwp   = (unsigned short*)pairsR;     // live: gemm1..agg1
    unsigned short* hts   = (unsigned short*)(pairsR + featB2); // live: agg1..agg2

    hipMemsetAsync(gh, 0, 512 * 4, stream);

    int nebk = (E + EPB - 1) / EPB;   // 391
    hist_k <<<nebk, 256, 0, stream>>>(dst, gh, E, nbk);
    scanb_k<<<1, 512, 0, stream>>>(gh, bbase, gcur, nbk);
    part_k <<<nebk, 256, 0, stream>>>(src, dst, gcur, pairs, E);
    build_k<<<nbk, 256, 0, stream>>>(pairs, bbase, rowptr, csr, dinv, n, nbk, E);

    gemm1_k<<<(n + GBM - 1) / GBM, 256, 0, stream>>>(x, W1, dinv, xwp, n);
    agg1_k<<<((size_t)n * 4 + 255) / 256, 256, 0, stream>>>(
        (const uint4*)xwp, rowptr, csr, dinv, b1, (uint4*)hts, n);
    agg2final_k<<<(n + 63) / 64, 256, 0, stream>>>(
        (const uint4*)hts, rowptr, csr, dinv, W2, b2, out, n);
}